// Round 14
// baseline (414.015 us; speedup 1.0000x reference)
//
#include <hip/hip_runtime.h>

// SparseAttention on MI355X.
// R6: attn rebuilt as canonical LDS-staged MFMA kernel:
//   - K staged per 128-row s-tile (3 bf16-split planes, 48KB), double-buffered;
//     Q staged per head (12KB). Reg-staged async split (T14): loads issued at
//     tile start, ds_write after compute, one barrier per tile.
//   - XOR swizzle (16B granule ^ (row&7)) applied at staging source AND
//     ds_read (both-sides involution) -> conflict-free LDS.
//   - Wave w = s-sub [w*16,+16) per tile; 2 q-row-tiles per wave; each K
//     fragment feeds 12 MFMAs. K tiles contiguous across heads (flat walk).
// proj/pv unchanged. 6-term bf16-split QK^T (fp32-equivalent, no flip risk).

#define THRESH 0.1f
#define PLANE (8 * 8 * 1024 * 64)   // elements per split plane [B][H][L][D]

typedef __attribute__((ext_vector_type(8))) short bf8_t;
typedef __attribute__((ext_vector_type(4))) float f4_t;

#define MFMA16(a, b, c) __builtin_amdgcn_mfma_f32_16x16x32_bf16(a, b, c, 0, 0, 0)

__device__ __forceinline__ unsigned short f2bf(float x) {  // RNE
  unsigned int u = __float_as_uint(x);
  u += 0x7FFFu + ((u >> 16) & 1u);
  return (unsigned short)(u >> 16);
}
__device__ __forceinline__ float bf2f(unsigned short h) {
  return __uint_as_float(((unsigned int)h) << 16);
}

// ---------------------------------------------------------------------------
// K1: fused projection GEMM (z=0: query@Wq^T+bq, z=1: key@Wk^T+bk). Unchanged.
// ---------------------------------------------------------------------------
__global__ __launch_bounds__(256) void proj_kernel(
    const float* __restrict__ query, const float* __restrict__ key,
    const float* __restrict__ Wq,    const float* __restrict__ Wk,
    const float* __restrict__ bq,    const float* __restrict__ bk,
    unsigned short* __restrict__ outq, unsigned short* __restrict__ outk)
{
  const int z = blockIdx.z;
  const float* A    = z ? key : query;
  const float* W    = z ? Wk  : Wq;
  const float* bias = z ? bk  : bq;
  unsigned short* outp = z ? outk : outq;

  __shared__ float As[16][132];
  __shared__ float Ws[16][68];
  const int t  = threadIdx.x;
  const int bm = blockIdx.x;
  const int bn = blockIdx.y;
  const int ty = t >> 4;
  const int tx = t & 15;
  const int lr  = t >> 2;
  const int lc4 = (t & 3) << 2;

  const float* Arow0 = A + (size_t)(bm * 128 + lr) * 512 + lc4;
  const float* Arow1 = Arow0 + 64 * 512;
  const float* Wrow  = W + (size_t)(bn * 64 + lr) * 512 + lc4;

  float acc[8][4] = {};

  float4 a0 = *(const float4*)(Arow0);
  float4 a1 = *(const float4*)(Arow1);
  float4 w0 = *(const float4*)(Wrow);

  for (int k0 = 0; k0 < 512; k0 += 16) {
    __syncthreads();
    As[lc4 + 0][lr] = a0.x; As[lc4 + 1][lr] = a0.y; As[lc4 + 2][lr] = a0.z; As[lc4 + 3][lr] = a0.w;
    As[lc4 + 0][lr + 64] = a1.x; As[lc4 + 1][lr + 64] = a1.y; As[lc4 + 2][lr + 64] = a1.z; As[lc4 + 3][lr + 64] = a1.w;
    Ws[lc4 + 0][lr] = w0.x; Ws[lc4 + 1][lr] = w0.y; Ws[lc4 + 2][lr] = w0.z; Ws[lc4 + 3][lr] = w0.w;
    __syncthreads();
    if (k0 + 16 < 512) {
      a0 = *(const float4*)(Arow0 + k0 + 16);
      a1 = *(const float4*)(Arow1 + k0 + 16);
      w0 = *(const float4*)(Wrow  + k0 + 16);
    }
    #pragma unroll
    for (int kk = 0; kk < 16; ++kk) {
      float4 av0 = *(const float4*)&As[kk][ty * 8];
      float4 av1 = *(const float4*)&As[kk][ty * 8 + 4];
      float4 bv0 = *(const float4*)&Ws[kk][tx * 4];
      float ar[8] = {av0.x, av0.y, av0.z, av0.w, av1.x, av1.y, av1.z, av1.w};
      float br[4] = {bv0.x, bv0.y, bv0.z, bv0.w};
      #pragma unroll
      for (int i = 0; i < 8; ++i)
        #pragma unroll
        for (int j = 0; j < 4; ++j)
          acc[i][j] += ar[i] * br[j];
    }
  }

  const int h = bn;
  #pragma unroll
  for (int i = 0; i < 8; ++i) {
    const int gr = bm * 128 + ty * 8 + i;
    const int l = gr >> 3;
    const int b = gr & 7;
    const int d = tx * 4;
    const size_t off = ((size_t)((b * 8 + h) * 1024 + l)) * 64 + d;
    ushort4 ph, pm, pl;
    #pragma unroll
    for (int q = 0; q < 4; ++q) {
      float x = acc[i][q] + bias[h * 64 + d + q];
      unsigned short b1 = f2bf(x);  float r1 = x  - bf2f(b1);
      unsigned short b2 = f2bf(r1); float r2 = r1 - bf2f(b2);
      unsigned short b3 = f2bf(r2);
      ((unsigned short*)&ph)[q] = b1;
      ((unsigned short*)&pm)[q] = b2;
      ((unsigned short*)&pl)[q] = b3;
    }
    *(ushort4*)&outp[off] = ph;
    *(ushort4*)&outp[(size_t)PLANE + off] = pm;
    *(ushort4*)&outp[(size_t)2 * PLANE + off] = pl;
  }
}

// ---------------------------------------------------------------------------
// K2: LDS-staged MFMA attention.
// Grid 256 (b=bx&7 -> XCD-local K), block 512 / 8 waves, 32 q-rows.
// Per head: 8 s-tiles of 128 rows. K tile = [pl][128][64] x2 buf (96KB),
// Q = [pl][32][64] (12KB), red = [8][32] (1KB). Swizzle: 16B granule
// stored at slot (c16 ^ (row&7)); staging reads source granule with the
// same involution so linear thread-order writes produce the swizzled image.
// Wave w: s-rows [w*16,+16) of each tile. qf[pl][rt][kc] in regs per head.
// C/D layout (m89): col=lane&15 (s), row=4*(lane>>4)+reg (q).
// ---------------------------------------------------------------------------
__global__ __launch_bounds__(512, 1) void attn_mfma_kernel(
    const unsigned short* __restrict__ qs,  // 3 planes [B][H][L][64]
    const unsigned short* __restrict__ ks,  // 3 planes [B][H][S][64]
    float* __restrict__ sw)                 // [B][L][S]
{
  const int bx = blockIdx.x;
  const int b  = bx & 7;
  const int l0 = (bx >> 3) << 5;    // 32 q-rows
  const int tid  = threadIdx.x;
  const int w    = tid >> 6;        // wave 0..7 = s-sub strip
  const int lane = tid & 63;
  const int c    = lane & 15;
  const int g    = lane >> 4;

  __shared__ unsigned short Kl[2][3][128 * 64];  // 96KB
  __shared__ unsigned short Ql[3][32 * 64];      // 12KB
  __shared__ float red[8][32];                   // 1KB

  // ---- per-thread staging geometry (K: 6 chunks of 16B; Q: 2 chunks) ----
  int kgo[6]; int klo[6];
  #pragma unroll
  for (int i = 0; i < 6; ++i) {
    const int pos  = i * 8192 + tid * 16;     // byte pos in 48KB tile image
    const int pl   = pos >> 14;
    const int rem  = pos & 16383;
    const int row  = rem >> 7;                // 0..127
    const int slot = (rem >> 4) & 7;          // stored 16B granule
    const int src  = slot ^ (row & 7);        // source granule (involution)
    kgo[i] = pl * PLANE + (b * 8192 + row) * 64 + src * 8;  // + T*8192 at use
    klo[i] = pl * 8192 + row * 64 + slot * 8;               // ushort idx in plane-major tile
  }
  int qgo[2]; int qlo[2];
  #pragma unroll
  for (int i = 0; i < 2; ++i) {
    const int pos  = i * 8192 + tid * 16;     // byte pos in 12KB Q image
    const int pl   = pos >> 12;
    const int rem  = pos & 4095;
    const int row  = rem >> 7;                // 0..31
    const int slot = (rem >> 4) & 7;
    const int src  = slot ^ (row & 7);
    qgo[i] = pl * PLANE + (b * 8192 + l0 + row) * 64 + src * 8;  // + h*65536 at use
    qlo[i] = pl * 2048 + row * 64 + slot * 8;
  }
  unsigned short* Kflat0 = &Kl[0][0][0];
  unsigned short* Kflat1 = &Kl[1][0][0];
  unsigned short* Qflat  = &Ql[0][0];

  // ---- prologue: stage K global-tile 0 into buf0, Q[0] ----
  {
    uint4 st[6];
    #pragma unroll
    for (int i = 0; i < 6; ++i) st[i] = *(const uint4*)(ks + kgo[i]);
    uint4 q0 = *(const uint4*)(qs + qgo[0]);
    uint4 q1 = {0,0,0,0};
    if (tid < 256) q1 = *(const uint4*)(qs + qgo[1]);
    #pragma unroll
    for (int i = 0; i < 6; ++i) *(uint4*)(Kflat0 + klo[i]) = st[i];
    *(uint4*)(Qflat + qlo[0]) = q0;
    if (tid < 256) *(uint4*)(Qflat + qlo[1]) = q1;
    __syncthreads();
  }

  f4_t avg[2][8];
  #pragma unroll
  for (int rt = 0; rt < 2; ++rt)
    #pragma unroll
    for (int t = 0; t < 8; ++t)
      avg[rt][t] = (f4_t){0.f, 0.f, 0.f, 0.f};

  // K-frag ds_read offsets (within a plane of the tile): row = w*16+c
  const int krow  = w * 16 + c;
  const int kst0  = (0 * 4 + g) ^ (krow & 7);   // kc=0 stored granule
  const int kst1  = (1 * 4 + g) ^ (krow & 7);   // kc=1
  const int koff0 = krow * 64 + kst0 * 8;
  const int koff1 = krow * 64 + kst1 * 8;

  for (int h = 0; h < 8; ++h) {
    bf8_t qf[3][2][2];
    f4_t acc[2][8];
    #pragma unroll
    for (int rt = 0; rt < 2; ++rt)
      #pragma unroll
      for (int t = 0; t < 8; ++t)
        acc[rt][t] = (f4_t){0.f, 0.f, 0.f, 0.f};

    #pragma unroll
    for (int t = 0; t < 8; ++t) {
      const int Tnext = h * 8 + t + 1;          // next global tile (0..63)
      const bool do_k = (Tnext < 64);
      const bool do_q = (h < 7) && (t == 1);

      // 1) issue staging loads (latency hides under this tile's compute)
      uint4 st[6];
      if (do_k) {
        #pragma unroll
        for (int i = 0; i < 6; ++i)
          st[i] = *(const uint4*)(ks + kgo[i] + Tnext * 8192);
      }
      uint4 q0 = {0,0,0,0}, q1 = {0,0,0,0};
      if (do_q) {
        q0 = *(const uint4*)(qs + qgo[0] + (h + 1) * 65536);
        if (tid < 256) q1 = *(const uint4*)(qs + qgo[1] + (h + 1) * 65536);
      }

      // 2) head start: Q fragments from LDS
      if (t == 0) {
        #pragma unroll
        for (int pl = 0; pl < 3; ++pl)
          #pragma unroll
          for (int rt = 0; rt < 2; ++rt)
            #pragma unroll
            for (int kc = 0; kc < 2; ++kc) {
              const int qrow = rt * 16 + c;
              const int qstl = (kc * 4 + g) ^ (qrow & 7);
              qf[pl][rt][kc] = *(const bf8_t*)(Qflat + pl * 2048 + qrow * 64 + qstl * 8);
            }
      }

      // 3) compute tile t from buf (t&1 == 0 -> buf0)
      {
        const unsigned short* Kb = (t & 1) ? Kflat1 : Kflat0;
        #pragma unroll
        for (int kc = 0; kc < 2; ++kc) {
          const int ko = kc ? koff1 : koff0;
          bf8_t kf0 = *(const bf8_t*)(Kb + 0 * 8192 + ko);
          bf8_t kf1 = *(const bf8_t*)(Kb + 1 * 8192 + ko);
          bf8_t kf2 = *(const bf8_t*)(Kb + 2 * 8192 + ko);
          #pragma unroll
          for (int rt = 0; rt < 2; ++rt) {
            acc[rt][t] = MFMA16(qf[0][rt][kc], kf0, acc[rt][t]);  // hh
            acc[rt][t] = MFMA16(qf[0][rt][kc], kf1, acc[rt][t]);  // hm
            acc[rt][t] = MFMA16(qf[1][rt][kc], kf0, acc[rt][t]);  // mh
            acc[rt][t] = MFMA16(qf[0][rt][kc], kf2, acc[rt][t]);  // hl
            acc[rt][t] = MFMA16(qf[1][rt][kc], kf1, acc[rt][t]);  // mm
            acc[rt][t] = MFMA16(qf[2][rt][kc], kf0, acc[rt][t]);  // lh
          }
        }
      }

      // 4) commit staged data to the other buffer
      if (do_k) {
        unsigned short* Kd = (t & 1) ? Kflat0 : Kflat1;
        #pragma unroll
        for (int i = 0; i < 6; ++i) *(uint4*)(Kd + klo[i]) = st[i];
      }
      if (do_q) {
        *(uint4*)(Qflat + qlo[0]) = q0;
        if (tid < 256) *(uint4*)(Qflat + qlo[1]) = q1;
      }
      __syncthreads();
    }

    // ---- softmax over S for this head ----
    const int ridx = g * 4;   // + reg; rows rt*16 + g*4 + reg
    float mrow[2][4];
    #pragma unroll
    for (int rt = 0; rt < 2; ++rt)
      #pragma unroll
      for (int reg = 0; reg < 4; ++reg) {
        float m = acc[rt][0][reg];
        #pragma unroll
        for (int t = 1; t < 8; ++t) m = fmaxf(m, acc[rt][t][reg]);
        #pragma unroll
        for (int off = 8; off > 0; off >>= 1) m = fmaxf(m, __shfl_xor(m, off));
        if (c == 0) red[w][rt * 16 + ridx + reg] = m;
      }
    __syncthreads();
    #pragma unroll
    for (int rt = 0; rt < 2; ++rt)
      #pragma unroll
      for (int reg = 0; reg < 4; ++reg) {
        float m = red[0][rt * 16 + ridx + reg];
        #pragma unroll
        for (int w2 = 1; w2 < 8; ++w2) m = fmaxf(m, red[w2][rt * 16 + ridx + reg]);
        mrow[rt][reg] = m;
      }
    __syncthreads();   // all reads of red done before sum writes

    float sloc[2][4] = {};
    #pragma unroll
    for (int rt = 0; rt < 2; ++rt)
      #pragma unroll
      for (int t = 0; t < 8; ++t)
        #pragma unroll
        for (int reg = 0; reg < 4; ++reg) {
          float p = __expf(0.125f * (acc[rt][t][reg] - mrow[rt][reg]));
          acc[rt][t][reg] = p;
          sloc[rt][reg] += p;
        }
    #pragma unroll
    for (int rt = 0; rt < 2; ++rt)
      #pragma unroll
      for (int reg = 0; reg < 4; ++reg) {
        float s = sloc[rt][reg];
        #pragma unroll
        for (int off = 8; off > 0; off >>= 1) s += __shfl_xor(s, off);
        if (c == 0) red[w][rt * 16 + ridx + reg] = s;
      }
    __syncthreads();
    #pragma unroll
    for (int rt = 0; rt < 2; ++rt)
      #pragma unroll
      for (int reg = 0; reg < 4; ++reg) {
        float s = red[0][rt * 16 + ridx + reg];
        #pragma unroll
        for (int w2 = 1; w2 < 8; ++w2) s += red[w2][rt * 16 + ridx + reg];
        const float inv = 0.125f / s;   // fold 1/H
        #pragma unroll
        for (int t = 0; t < 8; ++t)
          avg[rt][t][reg] += acc[rt][t][reg] * inv;
      }
    __syncthreads();   // red reads done before next head's writes
  }

  // ---- threshold + renormalize + store ----
  const int ridx = g * 4;
  float tl[2][4] = {};
  #pragma unroll
  for (int rt = 0; rt < 2; ++rt)
    #pragma unroll
    for (int t = 0; t < 8; ++t)
      #pragma unroll
      for (int reg = 0; reg < 4; ++reg) {
        float v = avg[rt][t][reg];
        v = v > THRESH ? v : 0.f;
        avg[rt][t][reg] = v;
        tl[rt][reg] += v;
      }
  #pragma unroll
  for (int rt = 0; rt < 2; ++rt)
    #pragma unroll
    for (int reg = 0; reg < 4; ++reg) {
      float s = tl[rt][reg];
      #pragma unroll
      for (int off = 8; off > 0; off >>= 1) s += __shfl_xor(s, off);
      if (c == 0) red[w][rt * 16 + ridx + reg] = s;
    }
  __syncthreads();
  #pragma unroll
  for (int rt = 0; rt < 2; ++rt)
    #pragma unroll
    for (int reg = 0; reg < 4; ++reg) {
      float s = red[0][rt * 16 + ridx + reg];
      #pragma unroll
      for (int w2 = 1; w2 < 8; ++w2) s += red[w2][rt * 16 + ridx + reg];
      const float inv = 1.f / (s + 1e-6f);
      const size_t rowoff = ((size_t)(b * 1024 + l0 + rt * 16 + ridx + reg)) * 1024;
      #pragma unroll
      for (int t = 0; t < 8; ++t)
        sw[rowoff + t * 128 + w * 16 + c] = avg[rt][t][reg] * inv;
    }
}

// ---------------------------------------------------------------------------
// K3: sparse PV (<=9 nnz/row guaranteed by threshold 0.1 + row-sum<=1).
// ---------------------------------------------------------------------------
__global__ __launch_bounds__(128) void pv_kernel(
    const float* __restrict__ sw,
    const float* __restrict__ value,
    float* __restrict__ out)
{
  const int l = blockIdx.x;
  const int b = blockIdx.y;
  const int t = threadIdx.x;
  __shared__ int cnt;
  __shared__ int   sidx[32];
  __shared__ float swt[32];
  if (t == 0) cnt = 0;
  __syncthreads();

  const float* row = sw + (size_t)(b * 1024 + l) * 1024;
  #pragma unroll
  for (int it = 0; it < 2; ++it) {
    const int s0 = (t + it * 128) * 4;
    float4 v = *(const float4*)(row + s0);
    if (v.x > 0.f) { int i = atomicAdd(&cnt, 1); if (i < 32) { sidx[i] = s0 + 0; swt[i] = v.x; } }
    if (v.y > 0.f) { int i = atomicAdd(&cnt, 1); if (i < 32) { sidx[i] = s0 + 1; swt[i] = v.y; } }
    if (v.z > 0.f) { int i = atomicAdd(&cnt, 1); if (i < 32) { sidx[i] = s0 + 2; swt[i] = v.z; } }
    if (v.w > 0.f) { int i = atomicAdd(&cnt, 1); if (i < 32) { sidx[i] = s0 + 3; swt[i] = v.w; } }
  }
  __syncthreads();
  const int n = cnt < 32 ? cnt : 32;

  const int e0 = t * 4;
  float4 o = {0.f, 0.f, 0.f, 0.f};
  for (int j = 0; j < n; ++j) {
    const float wgt = swt[j];
    const float4 vv = *(const float4*)(value + (size_t)(sidx[j] * 8 + b) * 512 + e0);
    o.x += wgt * vv.x; o.y += wgt * vv.y; o.z += wgt * vv.z; o.w += wgt * vv.w;
  }
  *(float4*)&out[(size_t)(l * 8 + b) * 512 + e0] = o;
}

// ---------------------------------------------------------------------------
extern "C" void kernel_launch(void* const* d_in, const int* in_sizes, int n_in,
                              void* d_out, int out_size, void* d_ws, size_t ws_size,
                              hipStream_t stream) {
  const float* query = (const float*)d_in[0];
  const float* key   = (const float*)d_in[1];
  const float* value = (const float*)d_in[2];
  const float* Wq    = (const float*)d_in[3];
  const float* bq    = (const float*)d_in[4];
  const float* Wk    = (const float*)d_in[5];
  const float* bk    = (const float*)d_in[6];

  float* out = (float*)d_out;
  float* sw  = out + (size_t)1024 * 8 * 512;

  unsigned short* qs = (unsigned short*)d_ws;          // 3 planes, 24 MB
  unsigned short* ks = qs + (size_t)3 * PLANE;         // 3 planes, 24 MB

  proj_kernel<<<dim3(64, 8, 2), 256, 0, stream>>>(query, key, Wq, Wk, bq, bk, qs, ks);
  attn_mfma_kernel<<<256, 512, 0, stream>>>(qs, ks, sw);
  pv_kernel<<<dim3(1024, 8), 128, 0, stream>>>(sw, value, out);
}